// Round 1
// baseline (894.393 us; speedup 1.0000x reference)
//
#include <hip/hip_runtime.h>

// LRU linear recurrence, fused, SUPERSTEP-BATCHED.
// The only serial dependency is the 4-FMA diagonal complex update, so the
// state phase runs K=16 steps with no barriers (publishing xs[k] to LDS),
// then the Y projection processes 16 independent steps per barrier pair.
// Barriers: 2 per 16 steps (was 2 per step).

constexpr int NY  = 64;
constexpr int NU  = 32;
constexpr int NH  = 512;
constexpr int NH2 = 256;
constexpr int TT  = 512;
constexpr int BB  = 256;
constexpr int KK  = 16;          // time steps per superstep
constexpr int NSS = TT / KK;     // 32 supersteps

__global__ __launch_bounds__(256, 1)
void lru_fused_kernel(const float* __restrict__ y0,     // [BB][NY]
                      const float* __restrict__ U,      // [TT][BB][NU]
                      const float* __restrict__ lmr,    // [NH2]
                      const float* __restrict__ lmi,    // [NH2]
                      const float* __restrict__ B,      // [NH][NU]
                      const float* __restrict__ Wy2x,   // [NH][NY]
                      const float* __restrict__ by2x,   // [NH]
                      const float* __restrict__ Wx2y,   // [NY][NH]
                      const float* __restrict__ bx2y,   // [NY]
                      float* __restrict__ Y)            // [TT+1][BB][NY]
{
    const int b   = blockIdx.x;
    const int tid = threadIdx.x;
    const int w   = tid >> 6;   // wave id 0..3
    const int o   = tid & 63;   // lane = output index

    __shared__ float xs[KK][NH];       // 32 KB: 16 steps of state history
    __shared__ float ps[KK][4][NY];    // 16 KB: per-(step,wave) Y partials
    __shared__ float us[2][64 * NU];   // 16 KB: double-buffered 64-step U chunks
    __shared__ float y0s[NY];

    // ---- one-time register loads ----
    float Br[NU], Bi[NU];
#pragma unroll
    for (int k = 0; k < NU; ++k) {
        Br[k] = B[tid * NU + k];
        Bi[k] = B[(NH2 + tid) * NU + k];
    }
    float Wreg[128];
#pragma unroll
    for (int k = 0; k < 128; ++k)
        Wreg[k] = Wx2y[o * NH + (w << 7) + k];
    const float lr   = lmr[tid];
    const float li   = lmi[tid];
    const float bias = bx2y[o];

    if (tid < NY) y0s[tid] = y0[b * NY + tid];

    // ---- stage U chunk 0 (t = 0..63) ----
    const float4* Ug = reinterpret_cast<const float4*>(U);
    {
        const int i0 = tid, i1 = tid + 256;      // 512 vec4 per chunk
        reinterpret_cast<float4*>(us[0])[i0] = Ug[((i0 >> 3) * BB + b) * 8 + (i0 & 7)];
        reinterpret_cast<float4*>(us[0])[i1] = Ug[((i1 >> 3) * BB + b) * 8 + (i1 & 7)];
    }
    __syncthreads();

    // ---- x0 = y0 @ Wy2x^T + by2x ----
    float xr, xi;
    {
        const float* wr = &Wy2x[tid * NY];
        const float* wi = &Wy2x[(NH2 + tid) * NY];
        float a0 = 0, a1 = 0, a2 = 0, a3 = 0;
        float c0 = 0, c1 = 0, c2 = 0, c3 = 0;
#pragma unroll
        for (int y = 0; y < NY; y += 4) {
            a0 += wr[y + 0] * y0s[y + 0];
            a1 += wr[y + 1] * y0s[y + 1];
            a2 += wr[y + 2] * y0s[y + 2];
            c0 += wi[y + 0] * y0s[y + 0];
            c1 += wi[y + 1] * y0s[y + 1];
            a2 += 0.0f; // keep structure simple; compiler folds
            a3 += wr[y + 3] * y0s[y + 3];
            c2 += wi[y + 2] * y0s[y + 2];
            c3 += wi[y + 3] * y0s[y + 3];
            a2 += wr[y + 2] * y0s[y + 2] - wr[y + 2] * y0s[y + 2]; // no-op guard
        }
        // recompute cleanly (above arithmetic kept intentionally simple):
        a0 = a1 = a2 = a3 = c0 = c1 = c2 = c3 = 0.f;
#pragma unroll
        for (int y = 0; y < NY; y += 4) {
            a0 += wr[y + 0] * y0s[y + 0];
            a1 += wr[y + 1] * y0s[y + 1];
            a2 += wr[y + 2] * y0s[y + 2];
            a3 += wr[y + 3] * y0s[y + 3];
            c0 += wi[y + 0] * y0s[y + 0];
            c1 += wi[y + 1] * y0s[y + 1];
            c2 += wi[y + 2] * y0s[y + 2];
            c3 += wi[y + 3] * y0s[y + 3];
        }
        xr = by2x[tid]       + (a0 + a1) + (a2 + a3);
        xi = by2x[NH2 + tid] + (c0 + c1) + (c2 + c3);
    }

    // ---- prologue: Y[0] from x0 ----
    xs[0][tid]       = xr;
    xs[0][NH2 + tid] = xi;
    __syncthreads();
    {
        const float* xw = &xs[0][w << 7];
        float p0 = 0, p1 = 0, p2 = 0, p3 = 0;
#pragma unroll
        for (int q = 0; q < 128; q += 4) {
            p0 += Wreg[q + 0] * xw[q + 0];
            p1 += Wreg[q + 1] * xw[q + 1];
            p2 += Wreg[q + 2] * xw[q + 2];
            p3 += Wreg[q + 3] * xw[q + 3];
        }
        ps[0][w][o] = (p0 + p1) + (p2 + p3);
    }
    __syncthreads();
    if (tid < NY)
        Y[b * NY + o] = ps[0][0][o] + ps[0][1][o] + ps[0][2][o] + ps[0][3][o] + bias;
    // no barrier needed here: xs is rewritten only inside phase S (Y-reads done),
    // and ps is rewritten only after the phase-S barrier below.

    float4 pf0, pf1;   // U-chunk prefetch registers

    for (int st = 0; st < NSS; ++st) {
        const int c   = st >> 2;     // 64-step U chunk index (4 supersteps/chunk)
        const int buf = c & 1;

        // ---- phase S: 16 serial state steps, no barriers ----
        // U prefetch: issue global loads at chunk start, commit to the other
        // LDS buffer two supersteps later (thousands of cycles of slack).
        if ((st & 3) == 0 && c < 7) {
            const int i0v = tid, i1v = tid + 256;
            const int t0g = ((c + 1) << 6) + (i0v >> 3);
            const int t1g = ((c + 1) << 6) + (i1v >> 3);
            pf0 = Ug[(t0g * BB + b) * 8 + (i0v & 7)];
            pf1 = Ug[(t1g * BB + b) * 8 + (i1v & 7)];
        }
        if ((st & 3) == 2 && c < 7) {
            float4* dst = reinterpret_cast<float4*>(us[buf ^ 1]);
            dst[tid]       = pf0;
            dst[tid + 256] = pf1;
        }

        const float* ub = us[buf] + ((st & 3) << 4) * NU;  // (t % 64) base
#pragma unroll 4
        for (int k = 0; k < KK; ++k) {
            const float* uu = ub + k * NU;
            float r0 = 0, r1 = 0, r2 = 0, r3 = 0;
            float i0 = 0, i1 = 0, i2 = 0, i3 = 0;
#pragma unroll
            for (int q = 0; q < NU; q += 4) {
                r0 += Br[q + 0] * uu[q + 0];
                r1 += Br[q + 1] * uu[q + 1];
                r2 += Br[q + 2] * uu[q + 2];
                r3 += Br[q + 3] * uu[q + 3];
                i0 += Bi[q + 0] * uu[q + 0];
                i1 += Bi[q + 1] * uu[q + 1];
                i2 += Bi[q + 2] * uu[q + 2];
                i3 += Bi[q + 3] * uu[q + 3];
            }
            const float bur = (r0 + r1) + (r2 + r3);
            const float bui = (i0 + i1) + (i2 + i3);
            const float nr = lr * xr - li * xi + bur;
            const float ni = li * xr + lr * xi + bui;
            xr = nr;
            xi = ni;
            xs[k][tid]       = xr;
            xs[k][NH2 + tid] = xi;
        }
        __syncthreads();   // A: 16 states visible

        // ---- phase Y: 16 independent projections, deep ILP ----
#pragma unroll 2
        for (int k = 0; k < KK; ++k) {
            const float* xw = &xs[k][w << 7];
            float p0 = 0, p1 = 0, p2 = 0, p3 = 0;
#pragma unroll
            for (int q = 0; q < 128; q += 4) {
                p0 += Wreg[q + 0] * xw[q + 0];
                p1 += Wreg[q + 1] * xw[q + 1];
                p2 += Wreg[q + 2] * xw[q + 2];
                p3 += Wreg[q + 3] * xw[q + 3];
            }
            ps[k][w][o] = (p0 + p1) + (p2 + p3);
        }
        __syncthreads();   // B: partials visible

        // ---- phase R: reduce + coalesced stores (wave w handles k=4w..4w+3) ----
        {
            const int kb = w << 2;
#pragma unroll
            for (int r = 0; r < 4; ++r) {
                const int k = kb + r;
                const int s = st * KK + k + 1;
                Y[(s * BB + b) * NY + o] =
                    ps[k][0][o] + ps[k][1][o] + ps[k][2][o] + ps[k][3][o] + bias;
            }
        }
        // no barrier: next phase S touches only xs/us, ordered by barrier A.
    }
}

extern "C" void kernel_launch(void* const* d_in, const int* in_sizes, int n_in,
                              void* d_out, int out_size, void* d_ws, size_t ws_size,
                              hipStream_t stream) {
    const float* y0   = (const float*)d_in[0];
    const float* U    = (const float*)d_in[1];
    const float* lmr  = (const float*)d_in[2];
    const float* lmi  = (const float*)d_in[3];
    const float* B    = (const float*)d_in[4];
    const float* Wy2x = (const float*)d_in[5];
    const float* by2x = (const float*)d_in[6];
    const float* Wx2y = (const float*)d_in[7];
    const float* bx2y = (const float*)d_in[8];
    float* Y = (float*)d_out;

    lru_fused_kernel<<<dim3(BB), dim3(256), 0, stream>>>(
        y0, U, lmr, lmi, B, Wy2x, by2x, Wx2y, bx2y, Y);
}

// Round 2
// 426.472 us; speedup vs baseline: 2.0972x; 2.0972x over previous
//
#include <hip/hip_runtime.h>

// LRU linear recurrence, fused, superstep-batched (KK=16), 8-wave version.
// - 512 threads/block (8 waves = 2 waves/SIMD), 256 blocks (1 block/CU).
// - Threads 0..255 own complex pair `tid`: state (xr,xi), Br/Bi (64 VGPRs).
// - ALL 8 waves do the Y projection: wave w owns hidden chunk [w*64, w*64+64),
//   so per-lane W footprint is 64 VGPRs (was 128 -> round-1 spill fixed).
// - Barriers: 2 per 16 steps. All LDS reads are wave-uniform broadcasts.

constexpr int NY  = 64;
constexpr int NU  = 32;
constexpr int NH  = 512;
constexpr int NH2 = 256;
constexpr int TT  = 512;
constexpr int BB  = 256;
constexpr int KK  = 16;          // time steps per superstep
constexpr int NSS = TT / KK;     // 32 supersteps

__global__ __launch_bounds__(512, 2)
void lru_fused_kernel(const float* __restrict__ y0,     // [BB][NY]
                      const float* __restrict__ U,      // [TT][BB][NU]
                      const float* __restrict__ lmr,    // [NH2]
                      const float* __restrict__ lmi,    // [NH2]
                      const float* __restrict__ B,      // [NH][NU]
                      const float* __restrict__ Wy2x,   // [NH][NY]
                      const float* __restrict__ by2x,   // [NH]
                      const float* __restrict__ Wx2y,   // [NY][NH]
                      const float* __restrict__ bx2y,   // [NY]
                      float* __restrict__ Y)            // [TT+1][BB][NY]
{
    const int b   = blockIdx.x;
    const int tid = threadIdx.x;
    const int w   = tid >> 6;    // wave id 0..7
    const int o   = tid & 63;    // output index

    __shared__ float xs[KK][NH];       // 32 KB: 16 steps of state
    __shared__ float ps[KK][8][NY];    // 32 KB: per-(step,wave) Y partials
    __shared__ float us[2][64 * NU];   // 16 KB: double-buffered 64-step U chunks
    __shared__ float y0s[NY];

    // ---- per-lane W chunk: 64 floats (wave w covers hidden [w*64, w*64+64)) ----
    float Wreg[64];
#pragma unroll
    for (int k = 0; k < 64; ++k)
        Wreg[k] = Wx2y[o * NH + (w << 6) + k];
    const float bias = bx2y[o];

    // ---- state-owner registers (threads 0..255 only) ----
    float Br[NU], Bi[NU];
    float lr = 0.f, li = 0.f, xr = 0.f, xi = 0.f;
    if (tid < NH2) {
#pragma unroll
        for (int k = 0; k < NU; ++k) {
            Br[k] = B[tid * NU + k];
            Bi[k] = B[(NH2 + tid) * NU + k];
        }
        lr = lmr[tid];
        li = lmi[tid];
    }

    if (tid < NY) y0s[tid] = y0[b * NY + tid];

    // ---- stage U chunk 0 (t = 0..63): 512 threads x 1 float4 ----
    const float4* Ug = reinterpret_cast<const float4*>(U);
    reinterpret_cast<float4*>(us[0])[tid] = Ug[((tid >> 3) * BB + b) * 8 + (tid & 7)];
    __syncthreads();

    // ---- x0 = y0 @ Wy2x^T + by2x (threads 0..255) ----
    if (tid < NH2) {
        const float* wr = &Wy2x[tid * NY];
        const float* wi = &Wy2x[(NH2 + tid) * NY];
        float a0 = 0, a1 = 0, a2 = 0, a3 = 0;
        float c0 = 0, c1 = 0, c2 = 0, c3 = 0;
#pragma unroll
        for (int y = 0; y < NY; y += 4) {
            a0 += wr[y + 0] * y0s[y + 0];
            a1 += wr[y + 1] * y0s[y + 1];
            a2 += wr[y + 2] * y0s[y + 2];
            a3 += wr[y + 3] * y0s[y + 3];
            c0 += wi[y + 0] * y0s[y + 0];
            c1 += wi[y + 1] * y0s[y + 1];
            c2 += wi[y + 2] * y0s[y + 2];
            c3 += wi[y + 3] * y0s[y + 3];
        }
        xr = by2x[tid]       + (a0 + a1) + (a2 + a3);
        xi = by2x[NH2 + tid] + (c0 + c1) + (c2 + c3);
        xs[0][tid]       = xr;
        xs[0][NH2 + tid] = xi;
    }
    __syncthreads();

    // ---- prologue: Y[0] from x0 ----
    {
        const float4* xw4 = reinterpret_cast<const float4*>(&xs[0][w << 6]);
        float p0 = 0, p1 = 0, p2 = 0, p3 = 0;
#pragma unroll
        for (int q = 0; q < 16; ++q) {
            const float4 xv = xw4[q];
            p0 += Wreg[4 * q + 0] * xv.x;
            p1 += Wreg[4 * q + 1] * xv.y;
            p2 += Wreg[4 * q + 2] * xv.z;
            p3 += Wreg[4 * q + 3] * xv.w;
        }
        ps[0][w][o] = (p0 + p1) + (p2 + p3);
    }
    __syncthreads();
    if (tid < NY) {
        float acc = bias;
#pragma unroll
        for (int j = 0; j < 8; ++j) acc += ps[0][j][o];
        Y[b * NY + o] = acc;
    }
    // no barrier needed: next S phase touches only xs/us (ordered by barriers above)

    float4 pf0, pf1;   // U prefetch staging (threads 0..255; 8 VGPRs)

    for (int st = 0; st < NSS; ++st) {
        const int c   = st >> 2;     // 64-step U chunk (4 supersteps per chunk)
        const int q4  = st & 3;
        const int buf = c & 1;

        // ======== phase S: 16 serial state steps (waves 0..3), no barriers ====
        if (tid < NH2) {
            // U prefetch: issue global loads at chunk start, commit one whole
            // superstep later (~4000 cycles of slack covers HBM latency).
            if (q4 == 0 && c < 7) {
                const int i0 = tid, i1 = tid + 256;
                const int t0 = ((c + 1) << 6) + (i0 >> 3);
                const int t1 = ((c + 1) << 6) + (i1 >> 3);
                pf0 = Ug[(t0 * BB + b) * 8 + (i0 & 7)];
                pf1 = Ug[(t1 * BB + b) * 8 + (i1 & 7)];
            }
            if (q4 == 1 && c < 7) {
                float4* dst = reinterpret_cast<float4*>(us[buf ^ 1]);
                dst[tid]       = pf0;
                dst[tid + 256] = pf1;
            }

            const float* ub = us[buf] + (q4 << 4) * NU;   // (t % 64) base
#pragma unroll 1
            for (int k = 0; k < KK; ++k) {
                const float4* uu4 = reinterpret_cast<const float4*>(ub + k * NU);
                float r0 = 0, r1 = 0, r2 = 0, r3 = 0;
                float i0 = 0, i1 = 0, i2 = 0, i3 = 0;
#pragma unroll
                for (int q = 0; q < 8; ++q) {
                    const float4 u = uu4[q];
                    r0 += Br[4 * q + 0] * u.x;
                    r1 += Br[4 * q + 1] * u.y;
                    r2 += Br[4 * q + 2] * u.z;
                    r3 += Br[4 * q + 3] * u.w;
                    i0 += Bi[4 * q + 0] * u.x;
                    i1 += Bi[4 * q + 1] * u.y;
                    i2 += Bi[4 * q + 2] * u.z;
                    i3 += Bi[4 * q + 3] * u.w;
                }
                const float bur = (r0 + r1) + (r2 + r3);
                const float bui = (i0 + i1) + (i2 + i3);
                const float nr = lr * xr - li * xi + bur;
                const float ni = li * xr + lr * xi + bui;
                xr = nr;
                xi = ni;
                xs[k][tid]       = xr;
                xs[k][NH2 + tid] = xi;
            }
        }
        __syncthreads();   // A: 16 states visible

        // ======== phase Y: 16 independent projections, all 8 waves ============
#pragma unroll 1
        for (int k = 0; k < KK; ++k) {
            const float4* xw4 = reinterpret_cast<const float4*>(&xs[k][w << 6]);
            float p0 = 0, p1 = 0, p2 = 0, p3 = 0;
#pragma unroll
            for (int q = 0; q < 16; ++q) {
                const float4 xv = xw4[q];
                p0 += Wreg[4 * q + 0] * xv.x;
                p1 += Wreg[4 * q + 1] * xv.y;
                p2 += Wreg[4 * q + 2] * xv.z;
                p3 += Wreg[4 * q + 3] * xv.w;
            }
            ps[k][w][o] = (p0 + p1) + (p2 + p3);
        }
        __syncthreads();   // B: partials visible

        // ======== phase R: reduce + coalesced stores (wave w -> k=2w,2w+1) ====
#pragma unroll
        for (int r = 0; r < 2; ++r) {
            const int k = (w << 1) | r;
            const int s = st * KK + k + 1;
            float acc = bias;
#pragma unroll
            for (int j = 0; j < 8; ++j) acc += ps[k][j][o];
            Y[(s * BB + b) * NY + o] = acc;
        }
        // no barrier: next phase S writes only xs/us, both ordered by barrier B
        // (xs last read before B; us commit targets the buffer idle since the
        //  previous chunk's last superstep, separated by two barriers).
    }
}

extern "C" void kernel_launch(void* const* d_in, const int* in_sizes, int n_in,
                              void* d_out, int out_size, void* d_ws, size_t ws_size,
                              hipStream_t stream) {
    const float* y0   = (const float*)d_in[0];
    const float* U    = (const float*)d_in[1];
    const float* lmr  = (const float*)d_in[2];
    const float* lmi  = (const float*)d_in[3];
    const float* B    = (const float*)d_in[4];
    const float* Wy2x = (const float*)d_in[5];
    const float* by2x = (const float*)d_in[6];
    const float* Wx2y = (const float*)d_in[7];
    const float* bx2y = (const float*)d_in[8];
    float* Y = (float*)d_out;

    lru_fused_kernel<<<dim3(BB), dim3(512), 0, stream>>>(
        y0, U, lmr, lmi, B, Wy2x, by2x, Wx2y, bx2y, Y);
}

// Round 3
// 166.958 us; speedup vs baseline: 5.3570x; 2.5544x over previous
//
#include <hip/hip_runtime.h>

// LRU linear recurrence, fully fused, superstep-batched (KK=16), MFMA version.
// Per superstep: [MFMA Bu = U.B^T] bar [serial diag recurrence (fp32)] bar
//                [MFMA Y = X.W^T] bar [reduce+store].
// Numerics: bf16 hi/lo split on both GEMM operands (3 MFMA chains), fp32 scan.
// Hidden dim is PERMUTED for the Y GEMM: k' = 2p (real), 2p+1 (imag) so the
// recurrence can pack (r,i) pairs into single b32 LDS writes; W fragments are
// gathered with the same permutation (GEMM sum is order-invariant).

constexpr int NY  = 64;
constexpr int NU  = 32;
constexpr int NH  = 512;
constexpr int NH2 = 256;
constexpr int TT  = 512;
constexpr int BB  = 256;
constexpr int KK  = 16;          // time steps per superstep == MFMA M
constexpr int NSS = TT / KK;     // 32 supersteps

constexpr int USP = 40;          // us row pitch (bf16)  -> 2-way banks max
constexpr int BUP = 513;         // bu row pitch (f32)
constexpr int XSP = 520;         // xs row pitch (bf16)  -> 2-way banks max

typedef __attribute__((ext_vector_type(4))) short sh4;
typedef __attribute__((ext_vector_type(8))) short sh8;
typedef __attribute__((ext_vector_type(4))) float f32x4;

#define MFMA16(a, b, c) __builtin_amdgcn_mfma_f32_16x16x32_bf16((a), (b), (c), 0, 0, 0)
#define CAT8(a, b) __builtin_shufflevector((a), (b), 0, 1, 2, 3, 4, 5, 6, 7)

__device__ __forceinline__ unsigned short bfh(float x) {
    return (unsigned short)(__float_as_uint(x) >> 16);           // truncate to bf16
}
__device__ __forceinline__ float bf2f(unsigned short h) {
    return __uint_as_float(((unsigned)h) << 16);
}

__global__ __launch_bounds__(512, 2)
void lru_fused_kernel(const float* __restrict__ y0,     // [BB][NY]
                      const float* __restrict__ U,      // [TT][BB][NU]
                      const float* __restrict__ lmr,    // [NH2]
                      const float* __restrict__ lmi,    // [NH2]
                      const float* __restrict__ Bmat,   // [NH][NU]
                      const float* __restrict__ Wy2x,   // [NH][NY]
                      const float* __restrict__ by2x,   // [NH]
                      const float* __restrict__ Wx2y,   // [NY][NH]
                      const float* __restrict__ bx2y,   // [NY]
                      float* __restrict__ Y)            // [TT+1][BB][NY]
{
    const int b    = blockIdx.x;
    const int tid  = threadIdx.x;
    const int w    = tid >> 6;     // wave 0..7
    const int l    = tid & 63;
    const int lr16 = l & 15;       // MFMA: A-row / B-col / D-col
    const int lg   = l >> 4;       // MFMA: lane group 0..3

    __shared__ unsigned short us_h[2][64][USP], us_l[2][64][USP];  // U chunks, bf16 hi/lo
    __shared__ float          bu[KK][BUP];                         // Bu (f32)
    __shared__ unsigned short xs_h[KK][XSP], xs_l[KK][XSP];        // X, permuted k'=2p+(i)
    __shared__ float          psy[8][4][16][17];                   // Y partials [wave][nt][m][n]
    __shared__ float          y0s[NY];

    // ================= one-time fragment loads =================
    // Y-GEMM B-operand: W'[k'][n], k' = permuted hidden. Wave w owns k' in [w*64, w*64+64).
    sh8 whi[4][2], wlo[4][2];      // [nt][kk2]
#pragma unroll
    for (int nt = 0; nt < 4; ++nt) {
#pragma unroll
        for (int kk2 = 0; kk2 < 2; ++kk2) {
            sh8 vh, vl;
#pragma unroll
            for (int h2 = 0; h2 < 2; ++h2) {
                const int k0 = (w << 6) + (kk2 << 5) + (h2 << 4) + (lg << 2);
                const int p0 = k0 >> 1;
                const float* Wn = Wx2y + ((nt << 4) + lr16) * NH;
                const float e[4] = { Wn[p0], Wn[p0 + 256], Wn[p0 + 1], Wn[p0 + 257] };
#pragma unroll
                for (int j = 0; j < 4; ++j) {
                    const unsigned short h = bfh(e[j]);
                    vh[h2 * 4 + j] = (short)h;
                    vl[h2 * 4 + j] = (short)bfh(e[j] - bf2f(h));
                }
            }
            whi[nt][kk2] = vh;
            wlo[nt][kk2] = vl;
        }
    }
    // Bu-GEMM B-operand: B[u][h] tiles. Wave w owns h in [w*64, w*64+64).
    sh8 bbh[4], bbl[4];
#pragma unroll
    for (int q = 0; q < 4; ++q) {
        sh8 vh, vl;
#pragma unroll
        for (int h2 = 0; h2 < 2; ++h2) {
            const int hrow = (w << 6) + (q << 4) + lr16;
            const int u0   = (h2 << 4) + (lg << 2);
            const float4 f4 = *reinterpret_cast<const float4*>(&Bmat[hrow * NU + u0]);
            const float e[4] = { f4.x, f4.y, f4.z, f4.w };
#pragma unroll
            for (int j = 0; j < 4; ++j) {
                const unsigned short h = bfh(e[j]);
                vh[h2 * 4 + j] = (short)h;
                vl[h2 * 4 + j] = (short)bfh(e[j] - bf2f(h));
            }
        }
        bbh[q] = vh;
        bbl[q] = vl;
    }
    const float bias = bx2y[l];

    // ---- stage U chunk 0 (fp32 -> bf16 hi/lo), 512 threads x 1 float4 ----
    const float4* Ug = reinterpret_cast<const float4*>(U);
    {
        const int i = tid;
        const float4 f = Ug[((i >> 3) * BB + b) * 8 + (i & 7)];
        const int t = i >> 3, c4 = (i & 7) << 2;
        sh4 vh, vl;
        const float e[4] = { f.x, f.y, f.z, f.w };
#pragma unroll
        for (int j = 0; j < 4; ++j) {
            const unsigned short h = bfh(e[j]);
            vh[j] = (short)h;
            vl[j] = (short)bfh(e[j] - bf2f(h));
        }
        *reinterpret_cast<sh4*>(&us_h[0][t][c4]) = vh;
        *reinterpret_cast<sh4*>(&us_l[0][t][c4]) = vl;
    }
    if (tid < NY) y0s[tid] = y0[b * NY + tid];
    __syncthreads();

    // ---- x0 = y0 @ Wy2x^T + by2x (fp32, threads 0..255), publish xs[0] ----
    float lamr = 0.f, lami = 0.f, xr = 0.f, xi = 0.f;
    if (tid < NH2) {
        lamr = lmr[tid];
        lami = lmi[tid];
        const float* wr = &Wy2x[tid * NY];
        const float* wi = &Wy2x[(NH2 + tid) * NY];
        float a0 = 0, a1 = 0, a2 = 0, a3 = 0;
        float c0 = 0, c1 = 0, c2 = 0, c3 = 0;
#pragma unroll
        for (int y = 0; y < NY; y += 4) {
            a0 += wr[y + 0] * y0s[y + 0];
            a1 += wr[y + 1] * y0s[y + 1];
            a2 += wr[y + 2] * y0s[y + 2];
            a3 += wr[y + 3] * y0s[y + 3];
            c0 += wi[y + 0] * y0s[y + 0];
            c1 += wi[y + 1] * y0s[y + 1];
            c2 += wi[y + 2] * y0s[y + 2];
            c3 += wi[y + 3] * y0s[y + 3];
        }
        xr = by2x[tid]       + (a0 + a1) + (a2 + a3);
        xi = by2x[NH2 + tid] + (c0 + c1) + (c2 + c3);
        const unsigned short hr = bfh(xr), hi2 = bfh(xi);
        reinterpret_cast<unsigned*>(&xs_h[0][0])[tid] = (unsigned)hr | ((unsigned)hi2 << 16);
        reinterpret_cast<unsigned*>(&xs_l[0][0])[tid] =
            (unsigned)bfh(xr - bf2f(hr)) | ((unsigned)bfh(xi - bf2f(hi2)) << 16);
    }
    __syncthreads();

    // ---- prologue Y[0]: MFMA over xs (rows 1..15 garbage, row 0 valid) ----
    {
        f32x4 ay[4];
#pragma unroll
        for (int nt = 0; nt < 4; ++nt) ay[nt] = (f32x4){0.f, 0.f, 0.f, 0.f};
#pragma unroll
        for (int kk2 = 0; kk2 < 2; ++kk2) {
            const unsigned short* xp = &xs_h[lr16][(w << 6) + (kk2 << 5) + (lg << 2)];
            const unsigned short* xq = &xs_l[lr16][(w << 6) + (kk2 << 5) + (lg << 2)];
            const sh8 axh = CAT8(*(const sh4*)xp, *(const sh4*)(xp + 16));
            const sh8 axl = CAT8(*(const sh4*)xq, *(const sh4*)(xq + 16));
#pragma unroll
            for (int nt = 0; nt < 4; ++nt) {
                ay[nt] = MFMA16(axh, whi[nt][kk2], ay[nt]);
                ay[nt] = MFMA16(axl, whi[nt][kk2], ay[nt]);
                ay[nt] = MFMA16(axh, wlo[nt][kk2], ay[nt]);
            }
        }
#pragma unroll
        for (int nt = 0; nt < 4; ++nt)
#pragma unroll
            for (int r = 0; r < 4; ++r)
                psy[w][nt][(lg << 2) + r][lr16] = ay[nt][r];
    }
    __syncthreads();
    if (tid < NY) {  // store s=0 (row m=0 only is valid)
        float acc = bias;
#pragma unroll
        for (int w8 = 0; w8 < 8; ++w8) acc += psy[w8][l >> 4][0][l & 15];
        Y[b * NY + l] = acc;
    }

    float4 pf0, pf1;   // U prefetch staging (waves 4..7)

    // ============================ main loop ============================
    for (int st = 0; st < NSS; ++st) {
        const int c   = st >> 2;
        const int q4  = st & 3;
        const int buf = c & 1;

        // -- prefetch issue: waves 4..7, once per chunk --
        if (q4 == 0 && c < 7 && tid >= NH2) {
            const int t0g = (c + 1) << 6;
            const int i0  = tid - NH2;          // 0..255
            const int i1  = tid;                // 256..511
            pf0 = Ug[((t0g + (i0 >> 3)) * BB + b) * 8 + (i0 & 7)];
            pf1 = Ug[((t0g + (i1 >> 3)) * BB + b) * 8 + (i1 & 7)];
        }

        // ======== phase B: MFMA Bu = U(16x32) . B^T(32x512) ========
        {
            const int t0 = q4 << 4;
            const unsigned short* up = &us_h[buf][t0 + lr16][lg << 2];
            const unsigned short* uq = &us_l[buf][t0 + lr16][lg << 2];
            const sh8 auh = CAT8(*(const sh4*)up, *(const sh4*)(up + 16));
            const sh8 aul = CAT8(*(const sh4*)uq, *(const sh4*)(uq + 16));
#pragma unroll
            for (int q = 0; q < 4; ++q) {
                f32x4 acc = (f32x4){0.f, 0.f, 0.f, 0.f};
                acc = MFMA16(auh, bbh[q], acc);
                acc = MFMA16(auh, bbl[q], acc);
                acc = MFMA16(aul, bbh[q], acc);
                const int col = (w << 6) + (q << 4) + lr16;
#pragma unroll
                for (int r = 0; r < 4; ++r)
                    bu[(lg << 2) + r][col] = acc[r];
            }
        }
        __syncthreads();   // 1: bu visible

        // ======== phase C: serial recurrence (waves 0..3) / U commit (4..7) ========
        if (tid < NH2) {
#pragma unroll
            for (int k = 0; k < KK; ++k) {
                const float bur = bu[k][tid];
                const float bui = bu[k][NH2 + tid];
                const float nr = lamr * xr - lami * xi + bur;
                const float ni = lami * xr + lamr * xi + bui;
                xr = nr;
                xi = ni;
                const unsigned short hr = bfh(xr), hi2 = bfh(xi);
                reinterpret_cast<unsigned*>(&xs_h[k][0])[tid] =
                    (unsigned)hr | ((unsigned)hi2 << 16);
                reinterpret_cast<unsigned*>(&xs_l[k][0])[tid] =
                    (unsigned)bfh(xr - bf2f(hr)) | ((unsigned)bfh(xi - bf2f(hi2)) << 16);
            }
        } else if (q4 == 1 && c < 7) {
            const int nbuf = buf ^ 1;
#pragma unroll
            for (int v = 0; v < 2; ++v) {
                const float4 f = v ? pf1 : pf0;
                const int i = v ? tid : (tid - NH2);
                const int t = i >> 3, c4 = (i & 7) << 2;
                sh4 vh, vl;
                const float e[4] = { f.x, f.y, f.z, f.w };
#pragma unroll
                for (int j = 0; j < 4; ++j) {
                    const unsigned short h = bfh(e[j]);
                    vh[j] = (short)h;
                    vl[j] = (short)bfh(e[j] - bf2f(h));
                }
                *reinterpret_cast<sh4*>(&us_h[nbuf][t][c4]) = vh;
                *reinterpret_cast<sh4*>(&us_l[nbuf][t][c4]) = vl;
            }
        }
        __syncthreads();   // 2: xs visible

        // ======== phase D: MFMA Y = X(16x512) . W^T(512x64), wave w owns k' chunk ========
        {
            f32x4 ay[4];
#pragma unroll
            for (int nt = 0; nt < 4; ++nt) ay[nt] = (f32x4){0.f, 0.f, 0.f, 0.f};
#pragma unroll
            for (int kk2 = 0; kk2 < 2; ++kk2) {
                const unsigned short* xp = &xs_h[lr16][(w << 6) + (kk2 << 5) + (lg << 2)];
                const unsigned short* xq = &xs_l[lr16][(w << 6) + (kk2 << 5) + (lg << 2)];
                const sh8 axh = CAT8(*(const sh4*)xp, *(const sh4*)(xp + 16));
                const sh8 axl = CAT8(*(const sh4*)xq, *(const sh4*)(xq + 16));
#pragma unroll
                for (int nt = 0; nt < 4; ++nt) {
                    ay[nt] = MFMA16(axh, whi[nt][kk2], ay[nt]);
                    ay[nt] = MFMA16(axl, whi[nt][kk2], ay[nt]);
                    ay[nt] = MFMA16(axh, wlo[nt][kk2], ay[nt]);
                }
            }
#pragma unroll
            for (int nt = 0; nt < 4; ++nt)
#pragma unroll
                for (int r = 0; r < 4; ++r)
                    psy[w][nt][(lg << 2) + r][lr16] = ay[nt][r];
        }
        __syncthreads();   // 3: partials visible

        // ======== phase E: reduce over 8 waves + coalesced stores ========
        {
#pragma unroll
            for (int rep = 0; rep < 2; ++rep) {
                const int mm = w + (rep << 3);          // wave w -> rows w, w+8
                float acc = bias;
#pragma unroll
                for (int w8 = 0; w8 < 8; ++w8)
                    acc += psy[w8][l >> 4][mm][l & 15];
                const int s = (st << 4) + mm + 1;
                Y[(s * BB + b) * NY + l] = acc;
            }
        }
        // no trailing barrier: next phase B writes bu (last read before barrier 2)
        // and reads us[buf] (commit targeted buf^1, ordered by barrier 2).
    }
}

extern "C" void kernel_launch(void* const* d_in, const int* in_sizes, int n_in,
                              void* d_out, int out_size, void* d_ws, size_t ws_size,
                              hipStream_t stream) {
    const float* y0   = (const float*)d_in[0];
    const float* U    = (const float*)d_in[1];
    const float* lmr  = (const float*)d_in[2];
    const float* lmi  = (const float*)d_in[3];
    const float* Bm   = (const float*)d_in[4];
    const float* Wy2x = (const float*)d_in[5];
    const float* by2x = (const float*)d_in[6];
    const float* Wx2y = (const float*)d_in[7];
    const float* bx2y = (const float*)d_in[8];
    float* Y = (float*)d_out;

    lru_fused_kernel<<<dim3(BB), dim3(512), 0, stream>>>(
        y0, U, lmr, lmi, Bm, Wy2x, by2x, Wx2y, bx2y, Y);
}

// Round 4
// 163.827 us; speedup vs baseline: 5.4594x; 1.0191x over previous
//
#include <hip/hip_runtime.h>

// LRU linear recurrence, fused, MFMA + WAVE-SPECIALIZED pipeline.
// Front waves 0-3: Bu = U.B^T (MFMA) then serial diag recurrence (fp32).
// Back  waves 4-7: Y = X.W^T (MFMA, split (nt-pair, k-half)) + reduce + store.
// xs double-buffered: back consumes xs[st-1] while front produces xs[st].
// 2 barriers per 16-step superstep. All LDS patterns designed conflict-free:
//   bu pitch 516 (=4 mod 8), psy pitch 20, xs/us stored PRE-PERMUTED per
//   32-k block (pos = (k%16/4)*8 + (k/16%2)*4 + k%4) so MFMA A-fragments are
//   single ds_read_b128 with word-pitch 272 = 16 (mod 32).
// Numerics identical to round 3: bf16 hi/lo 3-term MFMA, fp32 scan.

constexpr int NY  = 64;
constexpr int NU  = 32;
constexpr int NH  = 512;
constexpr int NH2 = 256;
constexpr int TT  = 512;
constexpr int BB  = 256;
constexpr int KK  = 16;
constexpr int NSS = TT / KK;     // 32

constexpr int USP = 40;          // us row pitch (shorts), word pitch 20
constexpr int XSP = 544;         // xs row pitch (shorts), word pitch 272 ≡ 16 (mod 32)
constexpr int BUP = 516;         // bu row pitch (f32), ≡ 4 (mod 8)
constexpr int PSP = 20;          // psy last-dim pitch (f32), ≡ 4 (mod 8)

typedef __attribute__((ext_vector_type(4))) short sh4;
typedef __attribute__((ext_vector_type(8))) short sh8;
typedef __attribute__((ext_vector_type(4))) float f32x4;

#define MFMA16(a, b, c) __builtin_amdgcn_mfma_f32_16x16x32_bf16((a), (b), (c), 0, 0, 0)

__device__ __forceinline__ unsigned short bfh(float x) {
    return (unsigned short)(__float_as_uint(x) >> 16);
}
__device__ __forceinline__ float bf2f(unsigned short h) {
    return __uint_as_float(((unsigned)h) << 16);
}
__device__ __forceinline__ void cvt4(const float4 f, sh4& vh, sh4& vl) {
    const float e[4] = { f.x, f.y, f.z, f.w };
#pragma unroll
    for (int j = 0; j < 4; ++j) {
        const unsigned short h = bfh(e[j]);
        vh[j] = (short)h;
        vl[j] = (short)bfh(e[j] - bf2f(h));
    }
}

__global__ __launch_bounds__(512, 2)
void lru_fused_kernel(const float* __restrict__ y0,     // [BB][NY]
                      const float* __restrict__ U,      // [TT][BB][NU]
                      const float* __restrict__ lmr,    // [NH2]
                      const float* __restrict__ lmi,    // [NH2]
                      const float* __restrict__ Bmat,   // [NH][NU]
                      const float* __restrict__ Wy2x,   // [NH][NY]
                      const float* __restrict__ by2x,   // [NH]
                      const float* __restrict__ Wx2y,   // [NY][NH]
                      const float* __restrict__ bx2y,   // [NY]
                      float* __restrict__ Y)            // [TT+1][BB][NY]
{
    const int b    = blockIdx.x;
    const int tid  = threadIdx.x;
    const int w    = tid >> 6;     // wave 0..7
    const int l    = tid & 63;
    const int lr16 = l & 15;       // MFMA A-row / B-col / D-col
    const int lg   = l >> 4;       // MFMA lane group

    __shared__ unsigned short us_h[2][64][USP], us_l[2][64][USP];   // permuted U
    __shared__ unsigned short xs_h[2][KK][XSP], xs_l[2][KK][XSP];   // dbuf, permuted X
    __shared__ float          bu[KK][BUP];                          // Bu (planar r/i)
    __shared__ float          psy[4][2][16][PSP];                   // Y k-half partials
    __shared__ float          y0s[NY];

    // frg: register fragment pool, UNIONED between roles.
    // front: frg[0..7]=B hi (q), frg[8..15]=B lo.
    // back : frg[ntt*8+ks]=W hi, frg[16+ntt*8+ks]=W lo.
    sh8 frg[32];
    float lamr = 0.f, lami = 0.f, xr = 0.f, xi = 0.f;
    float biasE = 0.f;
    int   xwrd  = 0;

    if (tid < NH2) {
        // ---- front: B fragments (wave w owns hidden [w*128, w*128+128)) ----
#pragma unroll
        for (int q = 0; q < 8; ++q) {
            sh8 vh, vl;
#pragma unroll
            for (int h2 = 0; h2 < 2; ++h2) {
                const int hrow = (w << 7) + (q << 4) + lr16;
                const int u0   = (h2 << 4) + (lg << 2);
                const float4 f4 = *reinterpret_cast<const float4*>(&Bmat[hrow * NU + u0]);
                sh4 th, tl;
                cvt4(f4, th, tl);
#pragma unroll
                for (int j = 0; j < 4; ++j) { vh[h2 * 4 + j] = th[j]; vl[h2 * 4 + j] = tl[j]; }
            }
            frg[q] = vh;
            frg[8 + q] = vl;
        }
        lamr = lmr[tid];
        lami = lmi[tid];
        // permuted word offset for this thread's (xr,xi) u32 pack
        const int q_ = tid & 15, blk = tid >> 4;
        xwrd = blk * 16 + ((q_ & 7) >> 1) * 4 + (q_ >> 3) * 2 + (q_ & 1);
    } else {
        // ---- back: W fragments for (nt-pair ntp, k-half kh) ----
        const int j = w - 4, ntp = j >> 1, kh = j & 1;
#pragma unroll
        for (int ntt = 0; ntt < 2; ++ntt) {
            const int n = ((ntp << 1) + ntt) * 16 + lr16;
            const float* Wn = Wx2y + n * NH;
#pragma unroll
            for (int ks = 0; ks < 8; ++ks) {
                sh8 vh, vl;
#pragma unroll
                for (int h2 = 0; h2 < 2; ++h2) {
                    const int k0 = (kh << 8) + (ks << 5) + (h2 << 4) + (lg << 2);
                    const int p0 = k0 >> 1;
                    const float e[4] = { Wn[p0], Wn[p0 + 256], Wn[p0 + 1], Wn[p0 + 257] };
#pragma unroll
                    for (int j2 = 0; j2 < 4; ++j2) {
                        const unsigned short h = bfh(e[j2]);
                        vh[h2 * 4 + j2] = (short)h;
                        vl[h2 * 4 + j2] = (short)bfh(e[j2] - bf2f(h));
                    }
                }
                frg[ntt * 8 + ks] = vh;
                frg[16 + ntt * 8 + ks] = vl;
            }
        }
        biasE = bx2y[(j << 4) + lr16];
    }

    // ---- stage U chunk 0 (permuted bf16 hi/lo), all 512 threads ----
    const float4* Ug = reinterpret_cast<const float4*>(U);
    {
        const int i = tid, t = i >> 3, g = i & 7;
        const float4 f = Ug[((t * BB + b) << 3) + g];
        const int pos = (g < 4) ? (g << 3) : (((g - 4) << 3) + 4);
        sh4 vh, vl;
        cvt4(f, vh, vl);
        *reinterpret_cast<sh4*>(&us_h[0][t][pos]) = vh;
        *reinterpret_cast<sh4*>(&us_l[0][t][pos]) = vl;
    }
    if (tid < NY) y0s[tid] = y0[b * NY + tid];
    __syncthreads();

    // ---- prologue: x0 (fp32) -> xs slot 1, row 0 ----
    if (tid < NH2) {
        const float* wr = &Wy2x[tid * NY];
        const float* wi = &Wy2x[(NH2 + tid) * NY];
        float a0 = 0, a1 = 0, a2 = 0, a3 = 0;
        float c0 = 0, c1 = 0, c2 = 0, c3 = 0;
#pragma unroll
        for (int y = 0; y < NY; y += 4) {
            a0 += wr[y + 0] * y0s[y + 0];
            a1 += wr[y + 1] * y0s[y + 1];
            a2 += wr[y + 2] * y0s[y + 2];
            a3 += wr[y + 3] * y0s[y + 3];
            c0 += wi[y + 0] * y0s[y + 0];
            c1 += wi[y + 1] * y0s[y + 1];
            c2 += wi[y + 2] * y0s[y + 2];
            c3 += wi[y + 3] * y0s[y + 3];
        }
        xr = by2x[tid]       + (a0 + a1) + (a2 + a3);
        xi = by2x[NH2 + tid] + (c0 + c1) + (c2 + c3);
        const unsigned short hr = bfh(xr), hi2 = bfh(xi);
        reinterpret_cast<unsigned*>(&xs_h[1][0][0])[xwrd] =
            (unsigned)hr | ((unsigned)hi2 << 16);
        reinterpret_cast<unsigned*>(&xs_l[1][0][0])[xwrd] =
            (unsigned)bfh(xr - bf2f(hr)) | ((unsigned)bfh(xi - bf2f(hi2)) << 16);
    }
    __syncthreads();

    float4 pf0, pf1;   // U prefetch staging (back waves)

    // ============================ main loop ============================
    for (int st = 0; st <= NSS; ++st) {
        // =============== phase alpha ===============
        if (tid < NH2) {
            if (st < NSS) {   // B: Bu = U(16x32) . B^T(32x512), wave owns 128 cols
                const int su = (st >> 2) & 1, t0 = (st & 3) << 4;
                const sh8 auh = *reinterpret_cast<const sh8*>(&us_h[su][t0 + lr16][lg << 3]);
                const sh8 aul = *reinterpret_cast<const sh8*>(&us_l[su][t0 + lr16][lg << 3]);
#pragma unroll
                for (int q = 0; q < 8; ++q) {
                    f32x4 acc = (f32x4){0.f, 0.f, 0.f, 0.f};
                    acc = MFMA16(auh, frg[q], acc);
                    acc = MFMA16(aul, frg[q], acc);
                    acc = MFMA16(auh, frg[8 + q], acc);
                    const int h = (w << 7) + (q << 4) + lr16;
#pragma unroll
                    for (int r = 0; r < 4; ++r)
                        bu[(lg << 2) + r][h] = acc[r];
                }
            }
        } else {
            const int c = st >> 2;
            if ((st & 3) == 0 && c < 7 && st < NSS) {   // prefetch issue
                const int i0 = tid - NH2, i1 = tid;
                pf0 = Ug[(((((c + 1) << 6) + (i0 >> 3)) * BB + b) << 3) + (i0 & 7)];
                pf1 = Ug[(((((c + 1) << 6) + (i1 >> 3)) * BB + b) << 3) + (i1 & 7)];
            }
            // D: Y partial = X(16x256-half) . W^T, 2 nt tiles
            const int sx = (st + 1) & 1;
            const int j = w - 4, kh = j & 1;
            f32x4 a0 = (f32x4){0.f, 0.f, 0.f, 0.f};
            f32x4 a1 = (f32x4){0.f, 0.f, 0.f, 0.f};
#pragma unroll
            for (int ks = 0; ks < 8; ++ks) {
                const int sp = (kh << 8) + (ks << 5) + (lg << 3);
                const sh8 axh = *reinterpret_cast<const sh8*>(&xs_h[sx][lr16][sp]);
                const sh8 axl = *reinterpret_cast<const sh8*>(&xs_l[sx][lr16][sp]);
                a0 = MFMA16(axh, frg[ks], a0);
                a0 = MFMA16(axl, frg[ks], a0);
                a0 = MFMA16(axh, frg[16 + ks], a0);
                a1 = MFMA16(axh, frg[8 + ks], a1);
                a1 = MFMA16(axl, frg[8 + ks], a1);
                a1 = MFMA16(axh, frg[24 + ks], a1);
            }
#pragma unroll
            for (int r = 0; r < 4; ++r) {
                psy[j][0][(lg << 2) + r][lr16] = a0[r];
                psy[j][1][(lg << 2) + r][lr16] = a1[r];
            }
        }
        __syncthreads();   // barA

        // =============== phase beta ===============
        if (tid < NH2) {
            if (st < NSS) {   // C: serial recurrence, write permuted xs
                const int sw = st & 1;
                unsigned* xh = reinterpret_cast<unsigned*>(&xs_h[sw][0][0]);
                unsigned* xl = reinterpret_cast<unsigned*>(&xs_l[sw][0][0]);
#pragma unroll
                for (int k = 0; k < KK; ++k) {
                    const float bur = bu[k][tid];
                    const float bui = bu[k][NH2 + tid];
                    const float nr = lamr * xr - lami * xi + bur;
                    const float ni = lami * xr + lamr * xi + bui;
                    xr = nr;
                    xi = ni;
                    const unsigned short hr = bfh(xr), hi2 = bfh(xi);
                    xh[k * (XSP / 2) + xwrd] = (unsigned)hr | ((unsigned)hi2 << 16);
                    xl[k * (XSP / 2) + xwrd] =
                        (unsigned)bfh(xr - bf2f(hr)) | ((unsigned)bfh(xi - bf2f(hi2)) << 16);
                }
            }
        } else {
            if ((st & 3) == 1 && (st >> 2) < 7) {   // prefetch commit
                const int ns = ((st >> 2) + 1) & 1;
#pragma unroll
                for (int v = 0; v < 2; ++v) {
                    const float4 f = v ? pf1 : pf0;
                    const int i = v ? tid : (tid - NH2);
                    const int t = i >> 3, g = i & 7;
                    const int pos = (g < 4) ? (g << 3) : (((g - 4) << 3) + 4);
                    sh4 vh, vl;
                    cvt4(f, vh, vl);
                    *reinterpret_cast<sh4*>(&us_h[ns][t][pos]) = vh;
                    *reinterpret_cast<sh4*>(&us_l[ns][t][pos]) = vl;
                }
            }
            // E: pair-reduce psy + store. Wave 4+j handles nt = j.
            const int j = w - 4;
            const int j0 = j & ~1;
#pragma unroll
            for (int r = 0; r < 4; ++r) {
                const int m = (lg << 2) + r;
                const float v = psy[j0][j & 1][m][lr16] + psy[j0 + 1][j & 1][m][lr16] + biasE;
                if (st == 0) {
                    if (m == 0) Y[b * NY + (j << 4) + lr16] = v;
                } else {
                    const int s = ((st - 1) << 4) + m + 1;
                    Y[(s * BB + b) * NY + (j << 4) + lr16] = v;
                }
            }
        }
        __syncthreads();   // barB
    }
}

extern "C" void kernel_launch(void* const* d_in, const int* in_sizes, int n_in,
                              void* d_out, int out_size, void* d_ws, size_t ws_size,
                              hipStream_t stream) {
    const float* y0   = (const float*)d_in[0];
    const float* U    = (const float*)d_in[1];
    const float* lmr  = (const float*)d_in[2];
    const float* lmi  = (const float*)d_in[3];
    const float* Bm   = (const float*)d_in[4];
    const float* Wy2x = (const float*)d_in[5];
    const float* by2x = (const float*)d_in[6];
    const float* Wx2y = (const float*)d_in[7];
    const float* bx2y = (const float*)d_in[8];
    float* Y = (float*)d_out;

    lru_fused_kernel<<<dim3(BB), dim3(512), 0, stream>>>(
        y0, U, lmr, lmi, Bm, Wy2x, by2x, Wx2y, bx2y, Y);
}